// Round 8
// baseline (135.350 us; speedup 1.0000x reference)
//
#include <hip/hip_runtime.h>

// CropperQAT: 3-level RoIAlign (8x8, sampling_ratio=1, aligned=false) with
// fake-quantized ROI coords, channel-concat output [A, 192, 8, 8] fp32.
//
// R8: single fused kernel, NO transpose pass / NO intermediate. Each
// (roi,lvl) block stages its 9x9x64ch patch straight from NCHW fp32
// (576 row-segments x 3 dwordx4, deep MLP), converts to bf16 in-register,
// scatters into the R4 swizzled LDS tile via ds_write_b16 (2-way = free),
// then runs the proven R4 bilinear+store phase. Mandatory HBM traffic drops
// from ~380 MB (two-pass) to ~285 MB.

#define NCH 64

typedef unsigned int   u32;
typedef unsigned short u16;

__device__ __forceinline__ float fake_quant(float v) {
    float r = rintf(v * 4.0f);                 // round half to even, like np.round
    r = fminf(fmaxf(r, -32768.0f), 32767.0f);
    return r * 0.25f;
}

struct Prep { int lo, hi; float fr; bool valid; };
__device__ __forceinline__ Prep prep(float c, int L) {
    Prep r;
    r.valid = (c >= -1.0f) && (c <= (float)L);
    c = fmaxf(c, 0.0f);
    const int l0 = (int)floorf(c);
    const bool he = (l0 >= L - 1);
    r.lo = he ? (L - 1) : l0;
    r.hi = he ? (L - 1) : (l0 + 1);
    r.fr = (he ? (float)(L - 1) : c) - (float)r.lo;
    return r;
}

__device__ __forceinline__ u16 f2bf(float x) {          // RNE fp32 -> bf16
    u32 u = __float_as_uint(x);
    u += 0x7FFFu + ((u >> 16) & 1u);
    return (u16)(u >> 16);
}
__device__ __forceinline__ float bflo(u32 w) { return __uint_as_float(w << 16); }
__device__ __forceinline__ float bfhi(u32 w) { return __uint_as_float(w & 0xFFFF0000u); }

__global__ __launch_bounds__(256) void cropper_qat_fused(
    const float* __restrict__ f0, const float* __restrict__ f1,
    const float* __restrict__ f2, const float* __restrict__ pixel,
    const int* __restrict__ bidx, float* __restrict__ out)
{
    // 81 positions x 8 chunks (uint4 = 8 bf16 channels), XOR-swizzled: 10368 B
    __shared__ uint4 tile[81 * 8];

    const int a   = blockIdx.x;
    const int lvl = blockIdx.y;

    const float inv_s = (lvl == 0) ? 0.25f : (lvl == 1) ? 0.125f : 0.0625f;
    const int   L     = (lvl == 0) ? 256   : (lvl == 1) ? 128    : 64;
    const float* __restrict__ f = (lvl == 0) ? f0 : (lvl == 1) ? f1 : f2;

    const int   b  = bidx[a];
    const float px = pixel[2 * a];
    const float py = pixel[2 * a + 1];

    const float x1 = fake_quant(fmaxf(px * inv_s - 4.0f, 0.0f));
    const float y1 = fake_quant(fmaxf(py * inv_s - 4.0f, 0.0f));
    const float x2 = fake_quant(fmaxf(px * inv_s + 4.0f, 0.0f));
    const float y2 = fake_quant(fmaxf(py * inv_s + 4.0f, 0.0f));

    const float binw = fmaxf(x2 - x1, 1.0f) * 0.125f;   // multiples of 1/32
    const float binh = fmaxf(y2 - y1, 1.0f) * 0.125f;

    // uniform patch origin (prep is monotone in the sample coordinate)
    const int y_lo = prep(y1 + 0.5f * binh, L).lo;
    const int x_lo = prep(x1 + 0.5f * binw, L).lo;

    const int tid = threadIdx.x;

    // ---- stage 9x9x64 patch from NCHW fp32 -> bf16 swizzled LDS -------------
    // unit u = row*64 + c (576 units); thread handles u = tid, tid+256, tid+512.
    // All control flow is block- or wave-uniform; out-of-range columns/rows are
    // staged as clamped-garbage into LDS slots the compute phase never reads.
    {
        const int xs    = x_lo & ~3;                    // 16B-aligned col start
        const int off   = x_lo - xs;                    // 0..3 (block-uniform)
        const bool fastx = (xs + 12 <= L);              // block-uniform
        const float* __restrict__ fb = f + (size_t)b * NCH * L * L;
        u16* __restrict__ tl16 = (u16*)tile;

        #pragma unroll
        for (int it = 0; it < 3; ++it) {
            const int u = tid + it * 256;
            if (u < 576) {                              // wave-uniform
                const int row = u >> 6;                 // 0..8 (wave-uniform)
                const int c   = u & 63;                 // = lane
                const int row_g = (y_lo + row <= L - 1) ? (y_lo + row) : (L - 1);
                const float* __restrict__ rp =
                    fb + (size_t)c * L * L + (size_t)row_g * L;
                float v[12];
                if (fastx) {
                    const float4 a0 = *(const float4*)(rp + xs);
                    const float4 a1 = *(const float4*)(rp + xs + 4);
                    const float4 a2 = *(const float4*)(rp + xs + 8);
                    v[0] = a0.x; v[1] = a0.y; v[2]  = a0.z; v[3]  = a0.w;
                    v[4] = a1.x; v[5] = a1.y; v[6]  = a1.z; v[7]  = a1.w;
                    v[8] = a2.x; v[9] = a2.y; v[10] = a2.z; v[11] = a2.w;
                } else {                                // right-edge blocks only
                    #pragma unroll
                    for (int k = 0; k < 12; ++k) {
                        const int xg = (xs + k <= L - 1) ? (xs + k) : (L - 1);
                        v[k] = rp[xg];
                    }
                }
                const int cq = c >> 3;                  // chunk (8 ch per uint4)
                const int ce = c & 7;                   // halfword within chunk
                #pragma unroll
                for (int k = 0; k < 9; ++k) {           // col k; garbage cols unused
                    const int pos = row * 9 + k;
                    tl16[pos * 64 + (cq ^ (pos & 7)) * 8 + ce] = f2bf(v[off + k]);
                }
            }
        }
    }
    __syncthreads();

    // ---- per-thread bilinear from LDS (identical to R4) ---------------------
    const int p  = tid & 63;
    const int i  = p >> 3;
    const int j  = p & 7;
    const int c0 = tid >> 6;       // 16-channel group = chunks 2c0, 2c0+1

    const Prep py_ = prep(y1 + ((float)i + 0.5f) * binh, L);
    const Prep px_ = prep(x1 + ((float)j + 0.5f) * binw, L);
    const bool valid = py_.valid && px_.valid;

    const float wy0 = 1.0f - py_.fr, wy1 = py_.fr;
    const float wx0 = 1.0f - px_.fr, wx1 = px_.fr;
    const float w00 = wy0 * wx0, w01 = wy0 * wx1;
    const float w10 = wy1 * wx0, w11 = wy1 * wx1;

    const int r0 = (py_.lo - y_lo) * 9;
    const int r1 = (py_.hi - y_lo) * 9;
    const int pos00 = r0 + (px_.lo - x_lo);
    const int pos01 = r0 + (px_.hi - x_lo);
    const int pos10 = r1 + (px_.lo - x_lo);
    const int pos11 = r1 + (px_.hi - x_lo);

    float r[16];
    #pragma unroll
    for (int k = 0; k < 16; ++k) r[k] = 0.0f;

    #define CORNER(POS, W) {                                                  \
        const uint4 qa = tile[(POS) * 8 + ((2 * c0)     ^ ((POS) & 7))];      \
        const uint4 qb = tile[(POS) * 8 + ((2 * c0 + 1) ^ ((POS) & 7))];      \
        r[0]  += bflo(qa.x) * (W); r[1]  += bfhi(qa.x) * (W);                 \
        r[2]  += bflo(qa.y) * (W); r[3]  += bfhi(qa.y) * (W);                 \
        r[4]  += bflo(qa.z) * (W); r[5]  += bfhi(qa.z) * (W);                 \
        r[6]  += bflo(qa.w) * (W); r[7]  += bfhi(qa.w) * (W);                 \
        r[8]  += bflo(qb.x) * (W); r[9]  += bfhi(qb.x) * (W);                 \
        r[10] += bflo(qb.y) * (W); r[11] += bfhi(qb.y) * (W);                 \
        r[12] += bflo(qb.z) * (W); r[13] += bfhi(qb.z) * (W);                 \
        r[14] += bflo(qb.w) * (W); r[15] += bfhi(qb.w) * (W); }

    CORNER(pos00, w00)
    CORNER(pos01, w01)
    CORNER(pos10, w10)
    CORNER(pos11, w11)
    #undef CORNER

    float* __restrict__ outp =
        out + ((size_t)a * 192 + (size_t)lvl * NCH + (size_t)c0 * 16) * 64 + p;
    #pragma unroll
    for (int k = 0; k < 16; ++k)
        __builtin_nontemporal_store(valid ? r[k] : 0.0f, outp + (size_t)k * 64);
}

extern "C" void kernel_launch(void* const* d_in, const int* in_sizes, int n_in,
                              void* d_out, int out_size, void* d_ws, size_t ws_size,
                              hipStream_t stream) {
    const float* f0    = (const float*)d_in[0];
    const float* f1    = (const float*)d_in[1];
    const float* f2    = (const float*)d_in[2];
    const float* pixel = (const float*)d_in[3];
    const int*   bidx  = (const int*)d_in[4];
    float* out = (float*)d_out;
    const int A = in_sizes[4];   // 4096 rois

    cropper_qat_fused<<<dim3(A, 3), 256, 0, stream>>>(f0, f1, f2, pixel, bidx, out);
}

// Round 9
// 76.480 us; speedup vs baseline: 1.7697x; 1.7697x over previous
//
#include <hip/hip_runtime.h>

// CropperQAT: 3-level RoIAlign (8x8, sampling_ratio=1, aligned=false) with
// fake-quantized ROI coords, channel-concat output [A, 192, 8, 8] fp32.
//
// R9: two-pass (R7) structure; main kernel now processes TWO same-level ROIs
// per block: 2x 9x9x64ch bf16 patches in 20.7KB swizzled LDS, 1296 staging
// uint4 loads issued back-to-back before one barrier (2x MLP of R7), setup
// amortized. 7 blocks/CU (28 waves) vs R7's 8 (32) — betting ILP > occupancy.

#define NCH 64

typedef unsigned int   u32;
typedef unsigned short u16;
typedef float  vf4 __attribute__((ext_vector_type(4)));
typedef u32    vu2 __attribute__((ext_vector_type(2)));

__device__ __forceinline__ float fake_quant(float v) {
    float r = rintf(v * 4.0f);                 // round half to even, like np.round
    r = fminf(fmaxf(r, -32768.0f), 32767.0f);
    return r * 0.25f;
}

struct Prep { int lo, hi; float fr; bool valid; };
__device__ __forceinline__ Prep prep(float c, int L) {
    Prep r;
    r.valid = (c >= -1.0f) && (c <= (float)L);
    c = fmaxf(c, 0.0f);
    const int l0 = (int)floorf(c);
    const bool he = (l0 >= L - 1);
    r.lo = he ? (L - 1) : l0;
    r.hi = he ? (L - 1) : (l0 + 1);
    r.fr = (he ? (float)(L - 1) : c) - (float)r.lo;
    return r;
}

__device__ __forceinline__ u16 f2bf(float x) {          // RNE fp32 -> bf16
    u32 u = __float_as_uint(x);
    u += 0x7FFFu + ((u >> 16) & 1u);
    return (u16)(u >> 16);
}
__device__ __forceinline__ float bflo(u32 w) { return __uint_as_float(w << 16); }
__device__ __forceinline__ float bfhi(u32 w) { return __uint_as_float(w & 0xFFFF0000u); }

// ---------------- NCHW(fp32) -> NHWC(bf16) transpose, all 3 levels fused ----
__global__ __launch_bounds__(256) void nchw_to_nhwc_bf16(
    const float* __restrict__ f0, const float* __restrict__ f1,
    const float* __restrict__ f2, u16* __restrict__ n0,
    u16* __restrict__ n1, u16* __restrict__ n2)
{
    __shared__ float tile[64][65];
    const int t = threadIdx.x;
    const int b = blockIdx.y;
    const int g = blockIdx.x;
    const float* src; u16* dst; int HW; int tl;
    if (g < 1024)      { src = f0; dst = n0; HW = 65536; tl = g; }
    else if (g < 1280) { src = f1; dst = n1; HW = 16384; tl = g - 1024; }
    else               { src = f2; dst = n2; HW = 4096;  tl = g - 1280; }
    const int hw0 = tl * 64;
    const float* __restrict__ s = src + (size_t)b * 64 * HW + hw0;
    vu2* __restrict__ d = (vu2*)(dst + ((size_t)b * HW + hw0) * 64);

    const int xq = (t & 15) * 4;
    const int cb = t >> 4;                       // 0..15
    #pragma unroll
    for (int k = 0; k < 4; ++k) {
        const int c = k * 16 + cb;
        const vf4 v = __builtin_nontemporal_load(
            (const vf4*)(s + (size_t)c * HW + xq));
        tile[c][xq + 0] = v.x;
        tile[c][xq + 1] = v.y;
        tile[c][xq + 2] = v.z;
        tile[c][xq + 3] = v.w;
    }
    __syncthreads();

    #pragma unroll
    for (int k = 0; k < 4; ++k) {
        const int idx = k * 256 + t;
        const int pos = idx >> 4;
        const int c2  = idx & 15;
        vu2 w;
        w.x = (u32)f2bf(tile[4 * c2 + 0][pos])
            | ((u32)f2bf(tile[4 * c2 + 1][pos]) << 16);
        w.y = (u32)f2bf(tile[4 * c2 + 2][pos])
            | ((u32)f2bf(tile[4 * c2 + 3][pos]) << 16);
        __builtin_nontemporal_store(w, d + pos * 16 + c2);
    }
}

// ---------------- main kernel: 2 same-level ROIs per block ------------------
__global__ __launch_bounds__(256) void cropper_qat_bf16x2(
    const u16* __restrict__ g0, const u16* __restrict__ g1,
    const u16* __restrict__ g2, const float* __restrict__ pixel,
    const int* __restrict__ bidx, float* __restrict__ out)
{
    // 2 ROIs x 81 positions x 8 chunks (uint4 = 8 bf16 ch), XOR-swizzled
    __shared__ uint4 tile[2 * 648];

    const int lvl = blockIdx.y;
    const float inv_s = (lvl == 0) ? 0.25f : (lvl == 1) ? 0.125f : 0.0625f;
    const int   L     = (lvl == 0) ? 256   : (lvl == 1) ? 128    : 64;
    const u16* __restrict__ f = (lvl == 0) ? g0 : (lvl == 1) ? g1 : g2;

    const int tid = threadIdx.x;
    const int a0  = blockIdx.x * 2;

    float x1v[2], y1v[2], bwv[2], bhv[2];
    int   xlv[2], ylv[2];
    const u16* fbase[2];

    #pragma unroll
    for (int rr = 0; rr < 2; ++rr) {
        const int   a  = a0 + rr;
        const int   b  = bidx[a];
        const float px = pixel[2 * a];
        const float py = pixel[2 * a + 1];
        const float x1 = fake_quant(fmaxf(px * inv_s - 4.0f, 0.0f));
        const float y1 = fake_quant(fmaxf(py * inv_s - 4.0f, 0.0f));
        const float x2 = fake_quant(fmaxf(px * inv_s + 4.0f, 0.0f));
        const float y2 = fake_quant(fmaxf(py * inv_s + 4.0f, 0.0f));
        const float bw = fmaxf(x2 - x1, 1.0f) * 0.125f;   // multiples of 1/32
        const float bh = fmaxf(y2 - y1, 1.0f) * 0.125f;
        const int y_lo = prep(y1 + 0.5f * bh, L).lo;      // uniform patch origin
        const int x_lo = prep(x1 + 0.5f * bw, L).lo;
        x1v[rr] = x1; y1v[rr] = y1; bwv[rr] = bw; bhv[rr] = bh;
        xlv[rr] = x_lo; ylv[rr] = y_lo;
        fbase[rr] = f + ((size_t)b * L * L + (size_t)y_lo * L + x_lo) * NCH;
    }

    // ---- stage both 9x9 patches (1296 uint4 chunks) back-to-back ------------
    #pragma unroll
    for (int it = 0; it < 6; ++it) {
        const int u = tid + it * 256;
        if (u < 1296) {
            const int rr  = (u >= 648) ? 1 : 0;
            const int uu  = u - rr * 648;
            const int ly  = uu / 72;               // 9 rows
            const int rem = uu - ly * 72;          // 9 cols x 8 chunks
            const int pos = ly * 9 + (rem >> 3);
            const int c   = rem & 7;
            const uint4 v = *(const uint4*)(fbase[rr] + (size_t)ly * L * NCH + rem * 8);
            tile[rr * 648 + pos * 8 + (c ^ (pos & 7))] = v;
        }
    }
    __syncthreads();

    // ---- per-thread bilinear from LDS, both ROIs ----------------------------
    const int p  = tid & 63;
    const int i  = p >> 3;
    const int j  = p & 7;
    const int c0 = tid >> 6;       // 16-channel group = chunks 2c0, 2c0+1

    #pragma unroll
    for (int rr = 0; rr < 2; ++rr) {
        const Prep py_ = prep(y1v[rr] + ((float)i + 0.5f) * bhv[rr], L);
        const Prep px_ = prep(x1v[rr] + ((float)j + 0.5f) * bwv[rr], L);
        const bool valid = py_.valid && px_.valid;

        const float wy0 = 1.0f - py_.fr, wy1 = py_.fr;
        const float wx0 = 1.0f - px_.fr, wx1 = px_.fr;
        const float w00 = wy0 * wx0, w01 = wy0 * wx1;
        const float w10 = wy1 * wx0, w11 = wy1 * wx1;

        const int r0 = (py_.lo - ylv[rr]) * 9;
        const int r1 = (py_.hi - ylv[rr]) * 9;
        const int pos00 = r0 + (px_.lo - xlv[rr]);
        const int pos01 = r0 + (px_.hi - xlv[rr]);
        const int pos10 = r1 + (px_.lo - xlv[rr]);
        const int pos11 = r1 + (px_.hi - xlv[rr]);
        const uint4* __restrict__ tl = tile + rr * 648;

        float r[16];
        #pragma unroll
        for (int k = 0; k < 16; ++k) r[k] = 0.0f;

        #define CORNER(POS, W) {                                              \
            const uint4 qa = tl[(POS) * 8 + ((2 * c0)     ^ ((POS) & 7))];    \
            const uint4 qb = tl[(POS) * 8 + ((2 * c0 + 1) ^ ((POS) & 7))];    \
            r[0]  += bflo(qa.x) * (W); r[1]  += bfhi(qa.x) * (W);             \
            r[2]  += bflo(qa.y) * (W); r[3]  += bfhi(qa.y) * (W);             \
            r[4]  += bflo(qa.z) * (W); r[5]  += bfhi(qa.z) * (W);             \
            r[6]  += bflo(qa.w) * (W); r[7]  += bfhi(qa.w) * (W);             \
            r[8]  += bflo(qb.x) * (W); r[9]  += bfhi(qb.x) * (W);             \
            r[10] += bflo(qb.y) * (W); r[11] += bfhi(qb.y) * (W);             \
            r[12] += bflo(qb.z) * (W); r[13] += bfhi(qb.z) * (W);             \
            r[14] += bflo(qb.w) * (W); r[15] += bfhi(qb.w) * (W); }

        CORNER(pos00, w00)
        CORNER(pos01, w01)
        CORNER(pos10, w10)
        CORNER(pos11, w11)
        #undef CORNER

        float* __restrict__ outp =
            out + ((size_t)(a0 + rr) * 192 + (size_t)lvl * NCH + (size_t)c0 * 16) * 64 + p;
        #pragma unroll
        for (int k = 0; k < 16; ++k)
            __builtin_nontemporal_store(valid ? r[k] : 0.0f, outp + (size_t)k * 64);
    }
}

// ---------------- fallback: fp32 NCHW direct gather -------------------------
__global__ __launch_bounds__(256) void cropper_qat_nchw(
    const float* __restrict__ f0, const float* __restrict__ f1,
    const float* __restrict__ f2, const float* __restrict__ pixel,
    const int* __restrict__ bidx, float* __restrict__ out)
{
    const int a   = blockIdx.x;
    const int lvl = blockIdx.y;
    const float inv_s = (lvl == 0) ? 0.25f : (lvl == 1) ? 0.125f : 0.0625f;
    const int   L     = (lvl == 0) ? 256   : (lvl == 1) ? 128    : 64;
    const float* __restrict__ f = (lvl == 0) ? f0 : (lvl == 1) ? f1 : f2;

    const int   b  = bidx[a];
    const float px = pixel[2 * a];
    const float py = pixel[2 * a + 1];
    const float x1 = fake_quant(fmaxf(px * inv_s - 4.0f, 0.0f));
    const float y1 = fake_quant(fmaxf(py * inv_s - 4.0f, 0.0f));
    const float x2 = fake_quant(fmaxf(px * inv_s + 4.0f, 0.0f));
    const float y2 = fake_quant(fmaxf(py * inv_s + 4.0f, 0.0f));
    const float binw = fmaxf(x2 - x1, 1.0f) * 0.125f;
    const float binh = fmaxf(y2 - y1, 1.0f) * 0.125f;

    const int tid = threadIdx.x;
    const int p = tid & 63, i = p >> 3, j = p & 7, c0 = tid >> 6;

    const Prep py_ = prep(y1 + ((float)i + 0.5f) * binh, L);
    const Prep px_ = prep(x1 + ((float)j + 0.5f) * binw, L);
    const bool valid = py_.valid && px_.valid;
    const float wy0 = 1.0f - py_.fr, wy1 = py_.fr;
    const float wx0 = 1.0f - px_.fr, wx1 = px_.fr;
    const float w00 = wy0 * wx0, w01 = wy0 * wx1, w10 = wy1 * wx0, w11 = wy1 * wx1;

    const size_t HW = (size_t)L * L;
    const float* __restrict__ fb = f + (size_t)b * NCH * HW;
    const int o00 = py_.lo * L + px_.lo, o01 = py_.lo * L + px_.hi;
    const int o10 = py_.hi * L + px_.lo, o11 = py_.hi * L + px_.hi;
    float* __restrict__ outp = out + ((size_t)a * 192 + (size_t)lvl * NCH) * 64 + p;

    #pragma unroll 4
    for (int c = c0; c < NCH; c += 4) {
        const float* __restrict__ fc = fb + (size_t)c * HW;
        float val = ((fc[o00] * w00 + fc[o01] * w01) + fc[o10] * w10) + fc[o11] * w11;
        outp[(size_t)c * 64] = valid ? val : 0.0f;
    }
}

extern "C" void kernel_launch(void* const* d_in, const int* in_sizes, int n_in,
                              void* d_out, int out_size, void* d_ws, size_t ws_size,
                              hipStream_t stream) {
    const float* f0    = (const float*)d_in[0];
    const float* f1    = (const float*)d_in[1];
    const float* f2    = (const float*)d_in[2];
    const float* pixel = (const float*)d_in[3];
    const int*   bidx  = (const int*)d_in[4];
    float* out = (float*)d_out;
    const int A = in_sizes[4];   // 4096 rois

    // bf16 NHWC scratch + 128KB slop for fixed-9x9 over-read past n2
    const size_t NEED = (size_t)(16777216 + 4194304 + 1048576) * 2 + 131072;
    if (ws_size >= NEED && (A & 1) == 0) {
        u16* n0 = (u16*)d_ws;
        u16* n1 = n0 + 16777216;
        u16* n2 = n1 + 4194304;
        nchw_to_nhwc_bf16<<<dim3(1344, 4), 256, 0, stream>>>(f0, f1, f2, n0, n1, n2);
        cropper_qat_bf16x2<<<dim3(A / 2, 3), 256, 0, stream>>>(n0, n1, n2, pixel, bidx, out);
    } else {
        cropper_qat_nchw<<<dim3(A, 3), 256, 0, stream>>>(f0, f1, f2, pixel, bidx, out);
    }
}